// Round 2
// baseline (1416.967 us; speedup 1.0000x reference)
//
#include <hip/hip_runtime.h>
#include <hip/hip_bf16.h>

typedef __hip_bfloat16 bf16;

#define GNUM 256
#define LN_EPS 1e-5f
#define MSG_EPS 1e-7f
#define SEG_CHUNK 128

__device__ __forceinline__ float wave_sum64(float v){
  #pragma unroll
  for (int off = 32; off > 0; off >>= 1) v += __shfl_xor(v, off, 64);
  return v;
}

// flag=1 if float data is fp32, 0 if bf16.
// Even-position 16-bit words of fp32 N(0,0.02) data have ~uniform exponent bits
// (P[all 256 have exp<137] ~ 1e-70); genuine bf16 of that dist has exp <= ~123.
__global__ void k_detect(const unsigned short* __restrict__ u, int* __restrict__ flag){
  int j = threadIdx.x;
  int bad = 0;
  for (int k = j; k < 256; k += 64){
    unsigned short v = u[2*k];
    unsigned e = (v >> 7) & 0xFFu;
    if (e >= 137u) bad = 1;   // |val| > ~2^9 or inf/nan -> not plausible bf16 emb
  }
  unsigned long long m = __ballot(bad);
  if (j == 0) *flag = (m != 0ull) ? 1 : 0;
}

struct Params15 {
  const void* src[15];
  int n[15];
  int off[15];
};

__global__ void k_convert(Params15 P, const int* __restrict__ flag, float* __restrict__ dst){
  bool isf = (*flag != 0);
  for (int a = 0; a < 15; ++a){
    int n = P.n[a];
    float* d = dst + P.off[a];
    if (isf){
      const float* s = (const float*)P.src[a];
      for (int i = blockIdx.x*256 + threadIdx.x; i < n; i += gridDim.x*256) d[i] = s[i];
    } else {
      const bf16* s = (const bf16*)P.src[a];
      for (int i = blockIdx.x*256 + threadIdx.x; i < n; i += gridDim.x*256) d[i] = __bfloat162float(s[i]);
    }
  }
}

// h[i,:] = sum_f atom_emb[f, x[i,f], :] + vn_emb[:]
__global__ void k_encode_nodes(const int* __restrict__ x, const float* __restrict__ atom_emb,
                               const float* __restrict__ vn_emb, float* __restrict__ h, int n){
  int t = blockIdx.x * 256 + threadIdx.x;
  int i = t >> 6, j = t & 63;
  if (i >= n) return;
  float acc = vn_emb[j];
  #pragma unroll
  for (int f = 0; f < 9; ++f){
    int idx = x[i*9 + f];
    acc += atom_emb[(f*64 + idx)*64 + j];
  }
  h[t] = acc;
}

__global__ void k_vn_init(const float* __restrict__ vn_emb, float* __restrict__ vn){
  vn[blockIdx.x * 64 + threadIdx.x] = vn_emb[threadIdx.x];
}

// msg recomputed identically (bit-exact) in passes A and B: fp32, same op order.
__device__ __forceinline__ float edge_msg(const float* __restrict__ hin,
                                          const float* __restrict__ bond,
                                          const int* __restrict__ ea,
                                          int e, int s, int j){
  int a0 = ea[e*3 + 0], a1 = ea[e*3 + 1], a2 = ea[e*3 + 2];
  float ee = bond[a0*64 + j] + bond[(8 + a1)*64 + j] + bond[(16 + a2)*64 + j];
  return fmaxf(hin[(size_t)s*64 + j] + ee, 0.f) + MSG_EPS;
}

// Pass A: atomicMax(msg) into mmax[dst]. msg > 0 and mmax zero-init, so
// int-ordered max is exact and empty nodes keep 0 (matches isfinite->0 clamp).
__global__ void k_msg_max(const float* __restrict__ hin, const float* __restrict__ bond,
                          const int* __restrict__ ea, const int* __restrict__ src,
                          const int* __restrict__ dst, float* __restrict__ mmax, int E){
  int t = blockIdx.x * 256 + threadIdx.x;
  int e = t >> 6, j = t & 63;
  if (e >= E) return;
  int s = src[e], d = dst[e];
  float m = edge_msg(hin, bond, ea, e, s, j);
  atomicMax((int*)(mmax + (size_t)d*64 + j), __float_as_int(m));
}

// Pass B: ex = exp(msg - mmax[dst]); denom += ex; num += ex*msg.
// num/max(denom,1e-16) == segment_sum(alpha*msg) algebraically.
__global__ void k_softmax_acc(const float* __restrict__ hin, const float* __restrict__ bond,
                              const int* __restrict__ ea, const int* __restrict__ src,
                              const int* __restrict__ dst, const float* __restrict__ mmax,
                              float* __restrict__ denom, float* __restrict__ num, int E){
  int t = blockIdx.x * 256 + threadIdx.x;
  int e = t >> 6, j = t & 63;
  if (e >= E) return;
  int s = src[e], d = dst[e];
  float m = edge_msg(hin, bond, ea, e, s, j);
  float ex = __expf(m - mmax[(size_t)d*64 + j]);
  unsafeAtomicAdd(denom + (size_t)d*64 + j, ex);
  unsafeAtomicAdd(num   + (size_t)d*64 + j, ex * m);
}

// Pass C: t = hin + num/max(denom,1e-16);  h = t @ W + b (+ residual h)
// Layer 0 passes hin==h: each block reads only its own rows before writing them.
__global__ __launch_bounds__(256) void k_node_update(
    const float* __restrict__ hin, const float* __restrict__ denom,
    const float* __restrict__ num, const float* __restrict__ W,
    const float* __restrict__ bias, float* __restrict__ h, int use_res, int n){
  __shared__ float Ws[64*64];
  __shared__ float tl[4][64];
  int tid = threadIdx.x;
  for (int idx = tid; idx < 4096; idx += 256) Ws[idx] = W[idx];
  int w = tid >> 6, j = tid & 63;
  int v = blockIdx.x * 4 + w;
  float tv = 0.f;
  if (v < n){
    size_t o = (size_t)v*64 + j;
    float mm = num[o] / fmaxf(denom[o], 1e-16f);
    tv = hin[o] + mm;
  }
  tl[w][j] = tv;
  __syncthreads();
  if (v < n){
    float acc = bias[j];
    const float* trow = tl[w];
    #pragma unroll
    for (int kk = 0; kk < 64; ++kk) acc = fmaf(trow[kk], Ws[kk*64 + j], acc);
    size_t o = (size_t)v*64 + j;
    if (use_res) acc += h[o];
    h[o] = acc;
  }
}

// h2 = relu(layernorm(h, g, b)); one wave per row (D=64)
__global__ void k_ln_relu(const float* __restrict__ h, const float* __restrict__ g,
                          const float* __restrict__ b, float* __restrict__ h2, int n){
  int t = blockIdx.x * 256 + threadIdx.x;
  int v = t >> 6, j = t & 63;
  if (v >= n) return;
  float x = h[t];
  float mu = wave_sum64(x) * (1.f/64.f);
  float d = x - mu;
  float var = wave_sum64(d*d) * (1.f/64.f);
  float y = d * rsqrtf(var + LN_EPS) * g[j] + b[j];
  h2[t] = fmaxf(y, 0.f);
}

// vt[g,:] += sum over nodes i with batch[i]==g of h2[i,:]  (batch sorted)
__global__ void k_segsum(const float* __restrict__ h2, const int* __restrict__ batch,
                         float* __restrict__ vt, int n){
  int j = threadIdx.x;
  int i0 = blockIdx.x * SEG_CHUNK;
  if (i0 >= n) return;
  int i1 = min(i0 + SEG_CHUNK, n);
  int cur = batch[i0];
  float acc = 0.f;
  for (int i = i0; i < i1; ++i){
    int bb = batch[i];
    if (bb != cur){ unsafeAtomicAdd(vt + (size_t)cur*64 + j, acc); acc = 0.f; cur = bb; }
    acc += h2[(size_t)i*64 + j];
  }
  unsafeAtomicAdd(vt + (size_t)cur*64 + j, acc);
}

// out = relu(layernorm((in_a [+ in_b]) @ W + bias, g, be)); one wave per row
__global__ __launch_bounds__(64) void k_vn_mlp(
    const float* __restrict__ in_a, const float* __restrict__ in_b,
    const float* __restrict__ W, const float* __restrict__ bias,
    const float* __restrict__ g, const float* __restrict__ be,
    float* __restrict__ out){
  __shared__ float Ws[4096];
  __shared__ float row[64];
  int j = threadIdx.x, gg = blockIdx.x;
  for (int idx = j; idx < 4096; idx += 64) Ws[idx] = W[idx];
  float rv = in_a[gg*64 + j];
  if (in_b) rv += in_b[gg*64 + j];
  row[j] = rv;
  __syncthreads();
  float acc = bias[j];
  #pragma unroll
  for (int kk = 0; kk < 64; ++kk) acc = fmaf(row[kk], Ws[kk*64 + j], acc);
  float mu = wave_sum64(acc) * (1.f/64.f);
  float d = acc - mu;
  float var = wave_sum64(d*d) * (1.f/64.f);
  float y = d * rsqrtf(var + LN_EPS) * g[j] + be[j];
  out[gg*64 + j] = fmaxf(y, 0.f);
}

// hin = h2 + vn[batch]
__global__ void k_addvn(const float* __restrict__ h2, const float* __restrict__ vn,
                        const int* __restrict__ batch, float* __restrict__ hin, int n){
  int t = blockIdx.x * 256 + threadIdx.x;
  int i = t >> 6, j = t & 63;
  if (i >= n) return;
  hin[t] = h2[t] + vn[(size_t)batch[i]*64 + j];
}

__global__ void k_final_ln(const float* __restrict__ h, const float* __restrict__ g,
                           const float* __restrict__ b, const int* __restrict__ flag,
                           void* __restrict__ out, int n){
  int t = blockIdx.x * 256 + threadIdx.x;
  int v = t >> 6, j = t & 63;
  if (v >= n) return;
  float x = h[t];
  float mu = wave_sum64(x) * (1.f/64.f);
  float d = x - mu;
  float var = wave_sum64(d*d) * (1.f/64.f);
  float y = d * rsqrtf(var + LN_EPS) * g[j] + b[j];
  if (*flag) ((float*)out)[t] = y;
  else       ((bf16*)out)[t]  = __float2bfloat16(y);
}

extern "C" void kernel_launch(void* const* d_in, const int* in_sizes, int n_in,
                              void* d_out, int out_size, void* d_ws, size_t ws_size,
                              hipStream_t stream){
  const int* x          = (const int*)d_in[0];
  const int* edge_index = (const int*)d_in[1];
  const int* edge_attr  = (const int*)d_in[2];
  const int* batch      = (const int*)d_in[3];

  const int N = in_sizes[3];
  const int E = in_sizes[2] / 3;
  const int L = 4;

  // fp32 param table offsets (elements)
  const int P_ATOM = 0, P_BOND = 36864, P_GW = 38400, P_GB = 54784,
            P_NG = 55040, P_NB = 55296, P_VNE = 55552, P_W1 = 55616,
            P_B1 = 67904, P_G1 = 68096, P_BE1 = 68288, P_W2 = 68480,
            P_B2 = 80768, P_G2 = 80960, P_BE2 = 81152, P_END = 81344;

  char* ws = (char*)d_ws;
  size_t off = 0;
  auto alloc = [&](size_t bytes)->char*{
    char* p = ws + off; off += (bytes + 255) & ~(size_t)255; return p;
  };
  int*   flag  = (int*)alloc(256);
  float* par   = (float*)alloc((size_t)P_END * 4);
  float* h     = (float*)alloc((size_t)N*64*4);
  float* h2    = (float*)alloc((size_t)N*64*4);
  float* hin   = (float*)alloc((size_t)N*64*4);
  float* mmax  = (float*)alloc((size_t)N*64*4);   // mmax/denom/num contiguous:
  float* denom = (float*)alloc((size_t)N*64*4);   // one memset covers all three
  float* num   = (float*)alloc((size_t)N*64*4);
  float* vt    = (float*)alloc((size_t)GNUM*64*4);
  float* vt2   = (float*)alloc((size_t)GNUM*64*4);
  float* vn    = (float*)alloc((size_t)GNUM*64*4);
  (void)ws_size; (void)n_in; (void)out_size;

  Params15 P;
  const int offs[15] = {P_ATOM,P_BOND,P_GW,P_GB,P_NG,P_NB,P_VNE,P_W1,P_B1,P_G1,P_BE1,P_W2,P_B2,P_G2,P_BE2};
  for (int a = 0; a < 15; ++a){ P.src[a] = d_in[4+a]; P.n[a] = in_sizes[4+a]; P.off[a] = offs[a]; }

  int nodeGrid = (N*64 + 255) / 256;
  int edgeGrid = (E*64 + 255) / 256;
  const int* srcp = edge_index;
  const int* dstp = edge_index + E;

  k_detect<<<1, 64, 0, stream>>>((const unsigned short*)d_in[4], flag);
  k_convert<<<64, 256, 0, stream>>>(P, flag, par);
  k_encode_nodes<<<nodeGrid, 256, 0, stream>>>(x, par + P_ATOM, par + P_VNE, h, N);
  k_vn_init<<<GNUM, 64, 0, stream>>>(par + P_VNE, vn);

  for (int l = 0; l < L; ++l){
    const float* hsrc = (l == 0) ? h : hin;
    if (l > 0){
      k_ln_relu<<<nodeGrid, 256, 0, stream>>>(h, par + P_NG + (l-1)*64, par + P_NB + (l-1)*64, h2, N);
      hipMemsetAsync(vt, 0, (size_t)GNUM*64*4, stream);
      k_segsum<<<(N + SEG_CHUNK - 1)/SEG_CHUNK, 64, 0, stream>>>(h2, batch, vt, N);
      k_vn_mlp<<<GNUM, 64, 0, stream>>>(vt, vn, par + P_W1 + (l-1)*4096, par + P_B1 + (l-1)*64,
                                        par + P_G1 + (l-1)*64, par + P_BE1 + (l-1)*64, vt2);
      k_vn_mlp<<<GNUM, 64, 0, stream>>>(vt2, nullptr, par + P_W2 + (l-1)*4096, par + P_B2 + (l-1)*64,
                                        par + P_G2 + (l-1)*64, par + P_BE2 + (l-1)*64, vn);
      k_addvn<<<nodeGrid, 256, 0, stream>>>(h2, vn, batch, hin, N);
    }
    hipMemsetAsync(mmax, 0, (size_t)3*N*64*4, stream);
    k_msg_max<<<edgeGrid, 256, 0, stream>>>(hsrc, par + P_BOND, edge_attr, srcp, dstp, mmax, E);
    k_softmax_acc<<<edgeGrid, 256, 0, stream>>>(hsrc, par + P_BOND, edge_attr, srcp, dstp,
                                                mmax, denom, num, E);
    k_node_update<<<(N + 3)/4, 256, 0, stream>>>(hsrc, denom, num, par + P_GW + l*4096,
                                                 par + P_GB + l*64, h, l > 0 ? 1 : 0, N);
  }
  k_final_ln<<<nodeGrid, 256, 0, stream>>>(h, par + P_NG + 3*64, par + P_NB + 3*64, flag,
                                           d_out, N);
}

// Round 3
// 836.067 us; speedup vs baseline: 1.6948x; 1.6948x over previous
//
#include <hip/hip_runtime.h>
#include <hip/hip_bf16.h>

typedef __hip_bfloat16 bf16;

#define GNUM 256
#define LN_EPS 1e-5f
#define MSG_EPS 1e-7f
#define SEG_CHUNK 128

__device__ __forceinline__ float wave_sum64(float v){
  #pragma unroll
  for (int off = 32; off > 0; off >>= 1) v += __shfl_xor(v, off, 64);
  return v;
}

// flag=1 if float data is fp32, 0 if bf16 (even 16-bit words of fp32 data have
// ~uniform exponent bits; genuine bf16 N(0,0.02) has exp <= ~123).
__global__ void k_detect(const unsigned short* __restrict__ u, int* __restrict__ flag){
  int j = threadIdx.x;
  int bad = 0;
  for (int k = j; k < 256; k += 64){
    unsigned short v = u[2*k];
    unsigned e = (v >> 7) & 0xFFu;
    if (e >= 137u) bad = 1;
  }
  unsigned long long m = __ballot(bad);
  if (j == 0) *flag = (m != 0ull) ? 1 : 0;
}

struct Params15 {
  const void* src[15];
  int n[15];
  int off[15];
};

__global__ void k_convert(Params15 P, const int* __restrict__ flag, float* __restrict__ dst){
  bool isf = (*flag != 0);
  for (int a = 0; a < 15; ++a){
    int n = P.n[a];
    float* d = dst + P.off[a];
    if (isf){
      const float* s = (const float*)P.src[a];
      for (int i = blockIdx.x*256 + threadIdx.x; i < n; i += gridDim.x*256) d[i] = s[i];
    } else {
      const bf16* s = (const bf16*)P.src[a];
      for (int i = blockIdx.x*256 + threadIdx.x; i < n; i += gridDim.x*256) d[i] = __bfloat162float(s[i]);
    }
  }
}

// ---------------- CSR build (dst constant across layers; built once) ----------
__global__ void k_count(const int* __restrict__ dst, int* __restrict__ counts, int E){
  int e = blockIdx.x*256 + threadIdx.x;
  if (e < E) atomicAdd(counts + dst[e], 1);
}

// exclusive-scan counts[0..n) -> offs[0..n]; single block of 1024 (16 waves)
__global__ __launch_bounds__(1024) void k_scan(const int* __restrict__ counts,
                                               int* __restrict__ offs, int n){
  __shared__ int wsum[16];
  __shared__ int carry_sh;
  int tid = threadIdx.x, w = tid >> 6, lane = tid & 63;
  if (tid == 0){ carry_sh = 0; offs[0] = 0; }
  __syncthreads();
  for (int base = 0; base < n; base += 1024){
    int i = base + tid;
    int v = (i < n) ? counts[i] : 0;
    int incl = v;
    #pragma unroll
    for (int off = 1; off < 64; off <<= 1){
      int t = __shfl_up(incl, off, 64);
      if (lane >= off) incl += t;
    }
    if (lane == 63) wsum[w] = incl;
    __syncthreads();
    int carry = carry_sh;
    int woff = 0;
    for (int k = 0; k < w; ++k) woff += wsum[k];
    if (i < n) offs[i+1] = carry + woff + incl;
    __syncthreads();
    if (tid == 1023){
      int tot = 0;
      for (int k = 0; k < 16; ++k) tot += wsum[k];
      carry_sh = carry + tot;
    }
    __syncthreads();
  }
}

__global__ void k_scatter(const int* __restrict__ src, const int* __restrict__ dst,
                          const int* __restrict__ ea, int* __restrict__ cursor,
                          int* __restrict__ src_sorted, int* __restrict__ attr_sorted, int E){
  int e = blockIdx.x*256 + threadIdx.x;
  if (e >= E) return;
  int d = dst[e];
  int pos = atomicAdd(cursor + d, 1);
  src_sorted[pos]  = src[e];
  attr_sorted[pos] = ea[e*3] | (ea[e*3+1] << 8) | (ea[e*3+2] << 16);
}

// ------------------------------------------------------------------------------
__global__ void k_encode_nodes(const int* __restrict__ x, const float* __restrict__ atom_emb,
                               const float* __restrict__ vn_emb, float* __restrict__ h, int n){
  int t = blockIdx.x * 256 + threadIdx.x;
  int i = t >> 6, j = t & 63;
  if (i >= n) return;
  float acc = vn_emb[j];
  #pragma unroll
  for (int f = 0; f < 9; ++f){
    int idx = x[i*9 + f];
    acc += atom_emb[(f*64 + idx)*64 + j];
  }
  h[t] = acc;
}

__global__ void k_vn_init(const float* __restrict__ vn_emb, float* __restrict__ vn){
  vn[blockIdx.x * 64 + threadIdx.x] = vn_emb[threadIdx.x];
}

// Fused GENConv layer: per-node online-softmax aggregation over CSR in-edges,
// t = hin + m, then h_out = t @ W + bias (+ residual h_out's own row).
// hsrc != hdst (no in-place gather hazard). One wave per node, 4 nodes/block.
__global__ __launch_bounds__(256) void k_agg(
    const float* __restrict__ hsrc, const int* __restrict__ offs,
    const int* __restrict__ src_sorted, const int* __restrict__ attr_sorted,
    const float* __restrict__ bond, const float* __restrict__ W,
    const float* __restrict__ bias, float* __restrict__ hdst, int use_res, int n){
  __shared__ float Ws[4096];
  __shared__ float Bs[1536];
  __shared__ float tl[4][64];
  int tid = threadIdx.x;
  for (int idx = tid; idx < 4096; idx += 256) Ws[idx] = W[idx];
  for (int idx = tid; idx < 1536; idx += 256) Bs[idx] = bond[idx];
  __syncthreads();
  int w = tid >> 6, j = tid & 63;
  int v = blockIdx.x * 4 + w;
  float tv = 0.f;
  if (v < n){
    int e0 = offs[v], e1 = offs[v+1];
    float mx = -INFINITY, den = 0.f, num = 0.f;
    for (int e = e0; e < e1; ++e){
      int s = src_sorted[e];
      int a = attr_sorted[e];
      float ee = Bs[(a & 255)*64 + j]
               + Bs[(8 + ((a >> 8) & 255))*64 + j]
               + Bs[(16 + (a >> 16))*64 + j];
      float m = fmaxf(hsrc[(size_t)s*64 + j] + ee, 0.f) + MSG_EPS;
      float nm = fmaxf(mx, m);
      float sc = __expf(mx - nm);   // 0 on first iter (mx=-inf), 1 if max unchanged
      float ex = __expf(m - nm);
      den = den*sc + ex;
      num = num*sc + ex*m;
      mx = nm;
    }
    tv = hsrc[(size_t)v*64 + j] + num / fmaxf(den, 1e-16f);  // deg-0 -> m=0 (matches ref)
  }
  tl[w][j] = tv;
  __syncthreads();
  if (v < n){
    float acc = bias[j];
    const float* trow = tl[w];
    #pragma unroll
    for (int kk = 0; kk < 64; ++kk) acc = fmaf(trow[kk], Ws[kk*64 + j], acc);
    size_t o = (size_t)v*64 + j;
    if (use_res) acc += hdst[o];
    hdst[o] = acc;
  }
}

// h2 = relu(layernorm(h, g, b)); one wave per row (D=64)
__global__ void k_ln_relu(const float* __restrict__ h, const float* __restrict__ g,
                          const float* __restrict__ b, float* __restrict__ h2, int n){
  int t = blockIdx.x * 256 + threadIdx.x;
  int v = t >> 6, j = t & 63;
  if (v >= n) return;
  float x = h[t];
  float mu = wave_sum64(x) * (1.f/64.f);
  float d = x - mu;
  float var = wave_sum64(d*d) * (1.f/64.f);
  float y = d * rsqrtf(var + LN_EPS) * g[j] + b[j];
  h2[t] = fmaxf(y, 0.f);
}

// vt[g,:] += sum over nodes i with batch[i]==g of h2[i,:]  (batch sorted)
__global__ void k_segsum(const float* __restrict__ h2, const int* __restrict__ batch,
                         float* __restrict__ vt, int n){
  int j = threadIdx.x;
  int i0 = blockIdx.x * SEG_CHUNK;
  if (i0 >= n) return;
  int i1 = min(i0 + SEG_CHUNK, n);
  int cur = batch[i0];
  float acc = 0.f;
  for (int i = i0; i < i1; ++i){
    int bb = batch[i];
    if (bb != cur){ unsafeAtomicAdd(vt + (size_t)cur*64 + j, acc); acc = 0.f; cur = bb; }
    acc += h2[(size_t)i*64 + j];
  }
  unsafeAtomicAdd(vt + (size_t)cur*64 + j, acc);
}

// out = relu(layernorm((in_a [+ in_b]) @ W + bias, g, be)); one wave per row
__global__ __launch_bounds__(64) void k_vn_mlp(
    const float* __restrict__ in_a, const float* __restrict__ in_b,
    const float* __restrict__ W, const float* __restrict__ bias,
    const float* __restrict__ g, const float* __restrict__ be,
    float* __restrict__ out){
  __shared__ float Ws[4096];
  __shared__ float row[64];
  int j = threadIdx.x, gg = blockIdx.x;
  for (int idx = j; idx < 4096; idx += 64) Ws[idx] = W[idx];
  float rv = in_a[gg*64 + j];
  if (in_b) rv += in_b[gg*64 + j];
  row[j] = rv;
  __syncthreads();
  float acc = bias[j];
  #pragma unroll
  for (int kk = 0; kk < 64; ++kk) acc = fmaf(row[kk], Ws[kk*64 + j], acc);
  float mu = wave_sum64(acc) * (1.f/64.f);
  float d = acc - mu;
  float var = wave_sum64(d*d) * (1.f/64.f);
  float y = d * rsqrtf(var + LN_EPS) * g[j] + be[j];
  out[gg*64 + j] = fmaxf(y, 0.f);
}

// hin = h2 + vn[batch]
__global__ void k_addvn(const float* __restrict__ h2, const float* __restrict__ vn,
                        const int* __restrict__ batch, float* __restrict__ hin, int n){
  int t = blockIdx.x * 256 + threadIdx.x;
  int i = t >> 6, j = t & 63;
  if (i >= n) return;
  hin[t] = h2[t] + vn[(size_t)batch[i]*64 + j];
}

__global__ void k_final_ln(const float* __restrict__ h, const float* __restrict__ g,
                           const float* __restrict__ b, const int* __restrict__ flag,
                           void* __restrict__ out, int n){
  int t = blockIdx.x * 256 + threadIdx.x;
  int v = t >> 6, j = t & 63;
  if (v >= n) return;
  float x = h[t];
  float mu = wave_sum64(x) * (1.f/64.f);
  float d = x - mu;
  float var = wave_sum64(d*d) * (1.f/64.f);
  float y = d * rsqrtf(var + LN_EPS) * g[j] + b[j];
  if (*flag) ((float*)out)[t] = y;
  else       ((bf16*)out)[t]  = __float2bfloat16(y);
}

extern "C" void kernel_launch(void* const* d_in, const int* in_sizes, int n_in,
                              void* d_out, int out_size, void* d_ws, size_t ws_size,
                              hipStream_t stream){
  const int* x          = (const int*)d_in[0];
  const int* edge_index = (const int*)d_in[1];
  const int* edge_attr  = (const int*)d_in[2];
  const int* batch      = (const int*)d_in[3];

  const int N = in_sizes[3];
  const int E = in_sizes[2] / 3;
  const int L = 4;

  const int P_ATOM = 0, P_BOND = 36864, P_GW = 38400, P_GB = 54784,
            P_NG = 55040, P_NB = 55296, P_VNE = 55552, P_W1 = 55616,
            P_B1 = 67904, P_G1 = 68096, P_BE1 = 68288, P_W2 = 68480,
            P_B2 = 80768, P_G2 = 80960, P_BE2 = 81152, P_END = 81344;

  char* ws = (char*)d_ws;
  size_t off = 0;
  auto alloc = [&](size_t bytes)->char*{
    char* p = ws + off; off += (bytes + 255) & ~(size_t)255; return p;
  };
  int*   flag   = (int*)alloc(256);
  float* par    = (float*)alloc((size_t)P_END * 4);
  float* b0     = (float*)alloc((size_t)N*64*4);   // encoded h / hin
  float* b1     = (float*)alloc((size_t)N*64*4);   // residual stream h
  float* b2     = (float*)alloc((size_t)N*64*4);   // h2 scratch
  int*   counts = (int*)alloc((size_t)N*4);
  int*   offs   = (int*)alloc((size_t)(N+1)*4);
  int*   cursor = (int*)alloc((size_t)N*4);
  int*   src_s  = (int*)alloc((size_t)E*4);
  int*   attr_s = (int*)alloc((size_t)E*4);
  float* vt     = (float*)alloc((size_t)GNUM*64*4);
  float* vt2    = (float*)alloc((size_t)GNUM*64*4);
  float* vn     = (float*)alloc((size_t)GNUM*64*4);
  (void)ws_size; (void)n_in; (void)out_size;

  Params15 P;
  const int poffs[15] = {P_ATOM,P_BOND,P_GW,P_GB,P_NG,P_NB,P_VNE,P_W1,P_B1,P_G1,P_BE1,P_W2,P_B2,P_G2,P_BE2};
  for (int a = 0; a < 15; ++a){ P.src[a] = d_in[4+a]; P.n[a] = in_sizes[4+a]; P.off[a] = poffs[a]; }

  int nodeGrid = (N*64 + 255) / 256;
  int eGrid    = (E + 255) / 256;
  const int* srcp = edge_index;
  const int* dstp = edge_index + E;

  k_detect<<<1, 64, 0, stream>>>((const unsigned short*)d_in[4], flag);
  k_convert<<<64, 256, 0, stream>>>(P, flag, par);

  // CSR build (dst is constant across layers)
  hipMemsetAsync(counts, 0, (size_t)N*4, stream);
  k_count<<<eGrid, 256, 0, stream>>>(dstp, counts, E);
  k_scan<<<1, 1024, 0, stream>>>(counts, offs, N);
  hipMemcpyAsync(cursor, offs, (size_t)N*4, hipMemcpyDeviceToDevice, stream);
  k_scatter<<<eGrid, 256, 0, stream>>>(srcp, dstp, edge_attr, cursor, src_s, attr_s, E);

  k_encode_nodes<<<nodeGrid, 256, 0, stream>>>(x, par + P_ATOM, par + P_VNE, b0, N);
  k_vn_init<<<GNUM, 64, 0, stream>>>(par + P_VNE, vn);

  // layer 0: gather from b0, write b1 (no residual)
  k_agg<<<(N + 3)/4, 256, 0, stream>>>(b0, offs, src_s, attr_s, par + P_BOND,
                                       par + P_GW, par + P_GB, b1, 0, N);
  for (int l = 1; l < L; ++l){
    k_ln_relu<<<nodeGrid, 256, 0, stream>>>(b1, par + P_NG + (l-1)*64, par + P_NB + (l-1)*64, b2, N);
    hipMemsetAsync(vt, 0, (size_t)GNUM*64*4, stream);
    k_segsum<<<(N + SEG_CHUNK - 1)/SEG_CHUNK, 64, 0, stream>>>(b2, batch, vt, N);
    k_vn_mlp<<<GNUM, 64, 0, stream>>>(vt, vn, par + P_W1 + (l-1)*4096, par + P_B1 + (l-1)*64,
                                      par + P_G1 + (l-1)*64, par + P_BE1 + (l-1)*64, vt2);
    k_vn_mlp<<<GNUM, 64, 0, stream>>>(vt2, nullptr, par + P_W2 + (l-1)*4096, par + P_B2 + (l-1)*64,
                                      par + P_G2 + (l-1)*64, par + P_BE2 + (l-1)*64, vn);
    k_addvn<<<nodeGrid, 256, 0, stream>>>(b2, vn, batch, b0, N);
    k_agg<<<(N + 3)/4, 256, 0, stream>>>(b0, offs, src_s, attr_s, par + P_BOND,
                                         par + P_GW + l*4096, par + P_GB + l*64, b1, 1, N);
  }
  k_final_ln<<<nodeGrid, 256, 0, stream>>>(b1, par + P_NG + 3*64, par + P_NB + 3*64, flag,
                                           d_out, N);
}

// Round 4
// 731.072 us; speedup vs baseline: 1.9382x; 1.1436x over previous
//
#include <hip/hip_runtime.h>
#include <hip/hip_bf16.h>

typedef __hip_bfloat16 bf16;

#define GNUM 256
#define LN_EPS 1e-5f
#define MSG_EPS 1e-7f

__device__ __forceinline__ float wave_sum64(float v){
  #pragma unroll
  for (int off = 32; off > 0; off >>= 1) v += __shfl_xor(v, off, 64);
  return v;
}

// flag=1 if float data is fp32, 0 if bf16.
__global__ void k_detect(const unsigned short* __restrict__ u, int* __restrict__ flag){
  int j = threadIdx.x;
  int bad = 0;
  for (int k = j; k < 256; k += 64){
    unsigned short v = u[2*k];
    unsigned e = (v >> 7) & 0xFFu;
    if (e >= 137u) bad = 1;
  }
  unsigned long long m = __ballot(bad);
  if (j == 0) *flag = (m != 0ull) ? 1 : 0;
}

struct Params15 {
  const void* src[15];
  int n[15];
  int off[15];
};

__global__ void k_convert(Params15 P, const int* __restrict__ flag, float* __restrict__ dst){
  bool isf = (*flag != 0);
  for (int a = 0; a < 15; ++a){
    int n = P.n[a];
    float* d = dst + P.off[a];
    if (isf){
      const float* s = (const float*)P.src[a];
      for (int i = blockIdx.x*256 + threadIdx.x; i < n; i += gridDim.x*256) d[i] = s[i];
    } else {
      const bf16* s = (const bf16*)P.src[a];
      for (int i = blockIdx.x*256 + threadIdx.x; i < n; i += gridDim.x*256) d[i] = __bfloat162float(s[i]);
    }
  }
}

// ---------------- CSR build (dst constant across layers; built once) ----------
__global__ void k_count(const int* __restrict__ dst, int* __restrict__ counts, int E){
  int e = blockIdx.x*256 + threadIdx.x;
  if (e < E) atomicAdd(counts + dst[e], 1);
}

__global__ __launch_bounds__(1024) void k_scan(const int* __restrict__ counts,
                                               int* __restrict__ offs, int n){
  __shared__ int wsum[16];
  __shared__ int carry_sh;
  int tid = threadIdx.x, w = tid >> 6, lane = tid & 63;
  if (tid == 0){ carry_sh = 0; offs[0] = 0; }
  __syncthreads();
  for (int base = 0; base < n; base += 1024){
    int i = base + tid;
    int v = (i < n) ? counts[i] : 0;
    int incl = v;
    #pragma unroll
    for (int off = 1; off < 64; off <<= 1){
      int t = __shfl_up(incl, off, 64);
      if (lane >= off) incl += t;
    }
    if (lane == 63) wsum[w] = incl;
    __syncthreads();
    int carry = carry_sh;
    int woff = 0;
    for (int k = 0; k < w; ++k) woff += wsum[k];
    if (i < n) offs[i+1] = carry + woff + incl;
    __syncthreads();
    if (tid == 1023){
      int tot = 0;
      for (int k = 0; k < 16; ++k) tot += wsum[k];
      carry_sh = carry + tot;
    }
    __syncthreads();
  }
}

__global__ void k_scatter(const int* __restrict__ src, const int* __restrict__ dst,
                          const int* __restrict__ ea, int* __restrict__ cursor,
                          int* __restrict__ src_sorted, int* __restrict__ attr_sorted, int E){
  int e = blockIdx.x*256 + threadIdx.x;
  if (e >= E) return;
  int d = dst[e];
  int pos = atomicAdd(cursor + d, 1);
  src_sorted[pos]  = src[e];
  attr_sorted[pos] = ea[e*3] | (ea[e*3+1] << 8) | (ea[e*3+2] << 16);
}

// goffs[g] = first row of graph g (batch sorted); goffs[GNUM] = n
__global__ void k_goffs(const int* __restrict__ batch, int* __restrict__ goffs, int n){
  int g = blockIdx.x*256 + threadIdx.x;
  if (g > GNUM) return;
  if (g == GNUM){ goffs[GNUM] = n; return; }
  int lo = 0, hi = n;
  while (lo < hi){ int mid = (lo+hi)>>1; if (batch[mid] < g) lo = mid+1; else hi = mid; }
  goffs[g] = lo;
}

// ------------------------------------------------------------------------------
__global__ void k_encode_nodes(const int* __restrict__ x, const float* __restrict__ atom_emb,
                               const float* __restrict__ vn_emb, float* __restrict__ h, int n){
  int t = blockIdx.x * 256 + threadIdx.x;
  int i = t >> 6, j = t & 63;
  if (i >= n) return;
  float acc = vn_emb[j];
  #pragma unroll
  for (int f = 0; f < 9; ++f){
    int idx = x[i*9 + f];
    acc += atom_emb[(f*64 + idx)*64 + j];
  }
  h[t] = acc;
}

// Fused GENConv layer + LN epilogue.
// mode 0: hres[v] = h_new; h2out[v] = relu(LN(h_new));   (norm params ng/nb)
// mode 1: final layer: only write finalout = LN(h_new) (bf16/fp32 per flag)
__global__ __launch_bounds__(256) void k_agg(
    const float* __restrict__ hsrc, const int* __restrict__ offs,
    const int* __restrict__ src_sorted, const int* __restrict__ attr_sorted,
    const float* __restrict__ bond, const float* __restrict__ W,
    const float* __restrict__ bias, float* __restrict__ hres,
    float* __restrict__ h2out, void* __restrict__ finalout,
    const float* __restrict__ ng, const float* __restrict__ nb,
    const int* __restrict__ flag, int use_res, int mode, int n){
  __shared__ float Ws[4096];
  __shared__ float Bs[1536];
  __shared__ float tl[4][64];
  int tid = threadIdx.x;
  for (int idx = tid; idx < 4096; idx += 256) Ws[idx] = W[idx];
  for (int idx = tid; idx < 1536; idx += 256) Bs[idx] = bond[idx];
  __syncthreads();
  int w = tid >> 6, j = tid & 63;
  int v = blockIdx.x * 4 + w;
  float tv = 0.f;
  if (v < n){
    int e0 = offs[v], e1 = offs[v+1];
    float own = hsrc[(size_t)v*64 + j];
    if (e1 > e0){
      float mx = -INFINITY, den = 0.f, num = 0.f;
      for (int e = e0; e < e1; e += 8){
        float m[8];
        // 8 independent gathers in flight; invalid slots -> sentinel (exp -> 0).
        #pragma unroll
        for (int u = 0; u < 8; ++u){
          int ei = e + u;
          bool valid = ei < e1;
          int idx = valid ? ei : e0;
          int s = src_sorted[idx];
          int a = attr_sorted[idx];
          float eev = Bs[(a & 255)*64 + j]
                    + Bs[(8 + ((a >> 8) & 255))*64 + j]
                    + Bs[(16 + ((a >> 16) & 255))*64 + j];
          float hv = hsrc[(size_t)s*64 + j];
          float mm = fmaxf(hv + eev, 0.f) + MSG_EPS;
          m[u] = valid ? mm : -3.0e38f;
        }
        float mb = m[0];
        #pragma unroll
        for (int u = 1; u < 8; ++u) mb = fmaxf(mb, m[u]);
        float nm = fmaxf(mx, mb);       // >= MSG_EPS > sentinel (>=1 real edge/batch)
        float sc = __expf(mx - nm);     // 0 on first batch (mx = -inf)
        den *= sc; num *= sc;
        #pragma unroll
        for (int u = 0; u < 8; ++u){
          float ex = __expf(m[u] - nm); // pads: exp(-huge) = 0
          den += ex;
          num += ex * m[u];
        }
        mx = nm;
      }
      tv = own + num / fmaxf(den, 1e-16f);
    } else {
      tv = own;                          // deg-0: m = 0 (matches ref isfinite->0)
    }
  }
  tl[w][j] = tv;
  __syncthreads();
  if (v < n){
    float acc = bias[j];
    const float* trow = tl[w];
    #pragma unroll
    for (int kk = 0; kk < 64; ++kk) acc = fmaf(trow[kk], Ws[kk*64 + j], acc);
    size_t o = (size_t)v*64 + j;
    if (use_res) acc += hres[o];
    if (mode == 0) hres[o] = acc;
    float mu = wave_sum64(acc) * (1.f/64.f);
    float d = acc - mu;
    float var = wave_sum64(d*d) * (1.f/64.f);
    float y = d * rsqrtf(var + LN_EPS) * ng[j] + nb[j];
    if (mode == 0){
      h2out[o] = fmaxf(y, 0.f);
    } else {
      if (*flag) ((float*)finalout)[o] = y;
      else       ((bf16*)finalout)[o]  = __float2bfloat16(y);
    }
  }
}

// Fused virtualnode update: one block (1 wave) per graph.
// vt = segment_sum(h2, rows of g) + vn_old; vt2 = relu(LN(vt@W1+b1));
// vn_new = relu(LN(vt2@W2+b2)). All row-local -> no grid sync needed.
__global__ __launch_bounds__(64) void k_vn(
    const float* __restrict__ h2, const int* __restrict__ goffs,
    const float* __restrict__ vn_emb, float* __restrict__ vn,
    const float* __restrict__ W1, const float* __restrict__ b1,
    const float* __restrict__ g1, const float* __restrict__ be1,
    const float* __restrict__ W2, const float* __restrict__ b2,
    const float* __restrict__ g2, const float* __restrict__ be2,
    int first){
  __shared__ float Ws[4096];
  __shared__ float row[64];
  int j = threadIdx.x, g = blockIdx.x;
  const float4* W1v = (const float4*)W1;
  float4* Wsv = (float4*)Ws;
  for (int idx = j; idx < 1024; idx += 64) Wsv[idx] = W1v[idx];
  int r0 = goffs[g], r1 = goffs[g+1];
  float sum = 0.f;
  for (int i = r0; i < r1; ++i) sum += h2[(size_t)i*64 + j];
  float vold = first ? vn_emb[j] : vn[(size_t)g*64 + j];
  row[j] = sum + vold;
  __syncthreads();
  float acc = b1[j];
  #pragma unroll
  for (int k = 0; k < 64; ++k) acc = fmaf(row[k], Ws[k*64 + j], acc);
  float mu = wave_sum64(acc) * (1.f/64.f);
  float d = acc - mu;
  float var = wave_sum64(d*d) * (1.f/64.f);
  float y = fmaxf(d * rsqrtf(var + LN_EPS) * g1[j] + be1[j], 0.f);
  __syncthreads();
  const float4* W2v = (const float4*)W2;
  for (int idx = j; idx < 1024; idx += 64) Wsv[idx] = W2v[idx];
  row[j] = y;
  __syncthreads();
  float acc2 = b2[j];
  #pragma unroll
  for (int k = 0; k < 64; ++k) acc2 = fmaf(row[k], Ws[k*64 + j], acc2);
  mu = wave_sum64(acc2) * (1.f/64.f);
  d = acc2 - mu;
  var = wave_sum64(d*d) * (1.f/64.f);
  float y2 = fmaxf(d * rsqrtf(var + LN_EPS) * g2[j] + be2[j], 0.f);
  vn[(size_t)g*64 + j] = y2;
}

// hin = h2 + vn[batch]
__global__ void k_addvn(const float* __restrict__ h2, const float* __restrict__ vn,
                        const int* __restrict__ batch, float* __restrict__ hin, int n){
  int t = blockIdx.x * 256 + threadIdx.x;
  int i = t >> 6, j = t & 63;
  if (i >= n) return;
  hin[t] = h2[t] + vn[(size_t)batch[i]*64 + j];
}

extern "C" void kernel_launch(void* const* d_in, const int* in_sizes, int n_in,
                              void* d_out, int out_size, void* d_ws, size_t ws_size,
                              hipStream_t stream){
  const int* x          = (const int*)d_in[0];
  const int* edge_index = (const int*)d_in[1];
  const int* edge_attr  = (const int*)d_in[2];
  const int* batch      = (const int*)d_in[3];

  const int N = in_sizes[3];
  const int E = in_sizes[2] / 3;
  const int L = 4;

  const int P_ATOM = 0, P_BOND = 36864, P_GW = 38400, P_GB = 54784,
            P_NG = 55040, P_NB = 55296, P_VNE = 55552, P_W1 = 55616,
            P_B1 = 67904, P_G1 = 68096, P_BE1 = 68288, P_W2 = 68480,
            P_B2 = 80768, P_G2 = 80960, P_BE2 = 81152, P_END = 81344;

  char* ws = (char*)d_ws;
  size_t off = 0;
  auto alloc = [&](size_t bytes)->char*{
    char* p = ws + off; off += (bytes + 255) & ~(size_t)255; return p;
  };
  int*   flag   = (int*)alloc(256);
  float* par    = (float*)alloc((size_t)P_END * 4);
  float* b0     = (float*)alloc((size_t)N*64*4);   // hin (gather source)
  float* b1     = (float*)alloc((size_t)N*64*4);   // residual stream h
  float* b2     = (float*)alloc((size_t)N*64*4);   // h2 = relu(LN(h))
  int*   counts = (int*)alloc((size_t)N*4);
  int*   offs   = (int*)alloc((size_t)(N+1)*4);
  int*   cursor = (int*)alloc((size_t)N*4);
  int*   src_s  = (int*)alloc((size_t)E*4);
  int*   attr_s = (int*)alloc((size_t)E*4);
  int*   goffs  = (int*)alloc((size_t)(GNUM+1)*4);
  float* vn     = (float*)alloc((size_t)GNUM*64*4);
  (void)ws_size; (void)n_in; (void)out_size;

  Params15 P;
  const int poffs[15] = {P_ATOM,P_BOND,P_GW,P_GB,P_NG,P_NB,P_VNE,P_W1,P_B1,P_G1,P_BE1,P_W2,P_B2,P_G2,P_BE2};
  for (int a = 0; a < 15; ++a){ P.src[a] = d_in[4+a]; P.n[a] = in_sizes[4+a]; P.off[a] = poffs[a]; }

  int nodeGrid = (N*64 + 255) / 256;
  int eGrid    = (E + 255) / 256;
  const int* srcp = edge_index;
  const int* dstp = edge_index + E;

  k_detect<<<1, 64, 0, stream>>>((const unsigned short*)d_in[4], flag);
  k_convert<<<64, 256, 0, stream>>>(P, flag, par);

  hipMemsetAsync(counts, 0, (size_t)N*4, stream);
  k_count<<<eGrid, 256, 0, stream>>>(dstp, counts, E);
  k_scan<<<1, 1024, 0, stream>>>(counts, offs, N);
  hipMemcpyAsync(cursor, offs, (size_t)N*4, hipMemcpyDeviceToDevice, stream);
  k_scatter<<<eGrid, 256, 0, stream>>>(srcp, dstp, edge_attr, cursor, src_s, attr_s, E);
  k_goffs<<<2, 256, 0, stream>>>(batch, goffs, N);

  k_encode_nodes<<<nodeGrid, 256, 0, stream>>>(x, par + P_ATOM, par + P_VNE, b0, N);

  // layer 0: gather b0 -> h in b1, h2 in b2 (LN with norm[0])
  k_agg<<<(N + 3)/4, 256, 0, stream>>>(b0, offs, src_s, attr_s, par + P_BOND,
                                       par + P_GW, par + P_GB, b1, b2, nullptr,
                                       par + P_NG, par + P_NB, flag, 0, 0, N);
  for (int l = 1; l < L; ++l){
    k_vn<<<GNUM, 64, 0, stream>>>(b2, goffs, par + P_VNE, vn,
                                  par + P_W1 + (l-1)*4096, par + P_B1 + (l-1)*64,
                                  par + P_G1 + (l-1)*64, par + P_BE1 + (l-1)*64,
                                  par + P_W2 + (l-1)*4096, par + P_B2 + (l-1)*64,
                                  par + P_G2 + (l-1)*64, par + P_BE2 + (l-1)*64,
                                  l == 1 ? 1 : 0);
    k_addvn<<<nodeGrid, 256, 0, stream>>>(b2, vn, batch, b0, N);
    int mode = (l == L-1) ? 1 : 0;
    k_agg<<<(N + 3)/4, 256, 0, stream>>>(b0, offs, src_s, attr_s, par + P_BOND,
                                         par + P_GW + l*4096, par + P_GB + l*64,
                                         b1, b2, d_out,
                                         par + P_NG + l*64, par + P_NB + l*64,
                                         flag, 1, mode, N);
  }
}

// Round 5
// 445.192 us; speedup vs baseline: 3.1828x; 1.6421x over previous
//
#include <hip/hip_runtime.h>
#include <hip/hip_bf16.h>

typedef __hip_bfloat16 bf16;

#define GNUM 256
#define LN_EPS 1e-5f
#define MSG_EPS 1e-7f

typedef float f4v __attribute__((ext_vector_type(4)));
typedef short s8v __attribute__((ext_vector_type(8)));
typedef __bf16 b8v __attribute__((ext_vector_type(8)));

// MFMA wrapper: gfx950 builtin may want <8 x bf16> or <8 x short> depending on
// toolchain; SFINAE picks whichever signature type-checks.
template <typename V>
__device__ auto mfma_bf16_(V a, V b, f4v c, int)
    -> decltype(__builtin_amdgcn_mfma_f32_16x16x32_bf16(a, b, c, 0, 0, 0)) {
  return __builtin_amdgcn_mfma_f32_16x16x32_bf16(a, b, c, 0, 0, 0);
}
template <typename V>
__device__ f4v mfma_bf16_(V a, V b, f4v c, long) {
  return __builtin_amdgcn_mfma_f32_16x16x32_bf16(__builtin_bit_cast(s8v, a),
                                                 __builtin_bit_cast(s8v, b), c, 0, 0, 0);
}
__device__ __forceinline__ f4v mfma16(uint4 a, uint4 b, f4v c){
  return mfma_bf16_(__builtin_bit_cast(b8v, a), __builtin_bit_cast(b8v, b), c, 0);
}

__device__ __forceinline__ float bu2f(unsigned short u){
  unsigned v = ((unsigned)u) << 16; return __builtin_bit_cast(float, v);
}
__device__ __forceinline__ unsigned short f2bu(float f){
  unsigned u = __builtin_bit_cast(unsigned, f);
  return (unsigned short)((u + 0x7FFFu + ((u >> 16) & 1u)) >> 16);
}

__device__ __forceinline__ float wave_sum64(float v){
  #pragma unroll
  for (int off = 32; off > 0; off >>= 1) v += __shfl_xor(v, off, 64);
  return v;
}

// flag=1 if float data is fp32, 0 if bf16.
__global__ void k_detect(const unsigned short* __restrict__ u, int* __restrict__ flag){
  int j = threadIdx.x;
  int bad = 0;
  for (int k = j; k < 256; k += 64){
    unsigned short v = u[2*k];
    unsigned e = (v >> 7) & 0xFFu;
    if (e >= 137u) bad = 1;
  }
  unsigned long long m = __ballot(bad);
  if (j == 0) *flag = (m != 0ull) ? 1 : 0;
}

struct Params15 {
  const void* src[15];
  int n[15];
  int off[15];
};

__global__ void k_convert(Params15 P, const int* __restrict__ flag, float* __restrict__ dst){
  bool isf = (*flag != 0);
  for (int a = 0; a < 15; ++a){
    int n = P.n[a];
    float* d = dst + P.off[a];
    if (isf){
      const float* s = (const float*)P.src[a];
      for (int i = blockIdx.x*256 + threadIdx.x; i < n; i += gridDim.x*256) d[i] = s[i];
    } else {
      const bf16* s = (const bf16*)P.src[a];
      for (int i = blockIdx.x*256 + threadIdx.x; i < n; i += gridDim.x*256) d[i] = __bfloat162float(s[i]);
    }
  }
}

// ---------------- CSR build ----------------
__global__ void k_count(const int* __restrict__ dst, int* __restrict__ counts, int E){
  int e = blockIdx.x*256 + threadIdx.x;
  if (e < E) atomicAdd(counts + dst[e], 1);
}

__global__ __launch_bounds__(256) void k_scan1(const int* __restrict__ counts,
                                               int* __restrict__ offs,
                                               int* __restrict__ btot, int n){
  __shared__ int wsum[4];
  int tid = threadIdx.x, w = tid >> 6, lane = tid & 63;
  int i = blockIdx.x*256 + tid;
  int v = (i < n) ? counts[i] : 0;
  int incl = v;
  #pragma unroll
  for (int off = 1; off < 64; off <<= 1){
    int t = __shfl_up(incl, off, 64);
    if (lane >= off) incl += t;
  }
  if (lane == 63) wsum[w] = incl;
  __syncthreads();
  int woff = 0;
  for (int k = 0; k < w; ++k) woff += wsum[k];
  int tot = incl + woff;
  if (i < n) offs[i+1] = tot;
  if (tid == 255) btot[blockIdx.x] = tot;
}

__global__ __launch_bounds__(256) void k_scan2(const int* __restrict__ btot,
                                               int* __restrict__ bexc, int nb){
  __shared__ int wsum[4];
  __shared__ int carry_sh;
  int tid = threadIdx.x, w = tid >> 6, lane = tid & 63;
  if (tid == 0) carry_sh = 0;
  __syncthreads();
  for (int base = 0; base < nb; base += 256){
    int i = base + tid;
    int v = (i < nb) ? btot[i] : 0;
    int incl = v;
    #pragma unroll
    for (int off = 1; off < 64; off <<= 1){
      int t = __shfl_up(incl, off, 64);
      if (lane >= off) incl += t;
    }
    if (lane == 63) wsum[w] = incl;
    __syncthreads();
    int carry = carry_sh;
    int woff = 0;
    for (int k = 0; k < w; ++k) woff += wsum[k];
    if (i < nb) bexc[i] = carry + woff + incl - v;
    __syncthreads();
    if (tid == 0) carry_sh = carry + wsum[0] + wsum[1] + wsum[2] + wsum[3];
    __syncthreads();
  }
}

__global__ void k_scan3(int* __restrict__ offs, const int* __restrict__ bexc, int n){
  int i = blockIdx.x*256 + threadIdx.x;
  if (i == 0) offs[0] = 0;
  if (i < n) offs[i+1] += bexc[blockIdx.x];
}

__global__ void k_scatter(const int* __restrict__ src, const int* __restrict__ dst,
                          const int* __restrict__ ea, int* __restrict__ cursor,
                          int* __restrict__ src_sorted, int* __restrict__ attr_sorted, int E){
  int e = blockIdx.x*256 + threadIdx.x;
  if (e >= E) return;
  int d = dst[e];
  int pos = atomicAdd(cursor + d, 1);
  src_sorted[pos]  = src[e];
  attr_sorted[pos] = ea[e*3] | (ea[e*3+1] << 8) | (ea[e*3+2] << 16);
}

__global__ void k_goffs(const int* __restrict__ batch, int* __restrict__ goffs, int n){
  int g = blockIdx.x*256 + threadIdx.x;
  if (g > GNUM) return;
  if (g == GNUM){ goffs[GNUM] = n; return; }
  int lo = 0, hi = n;
  while (lo < hi){ int mid = (lo+hi)>>1; if (batch[mid] < g) lo = mid+1; else hi = mid; }
  goffs[g] = lo;
}

// Permute gcn_W into MFMA B-fragment order (bf16):
// Wf[(((l*2+kt)*4+nt)*64 + lane)*8 + j] = W_l[kt*32+(lane>>4)*8+j][nt*16+(lane&15)]
__global__ void k_prep_w(const float* __restrict__ gw, unsigned short* __restrict__ Wf){
  int t = blockIdx.x*256 + threadIdx.x;   // 16384 total
  int j = t & 7, lane = (t >> 3) & 63, nt = (t >> 9) & 3, kt = (t >> 11) & 1, l = t >> 12;
  int k = kt*32 + (lane >> 4)*8 + j;
  int c = nt*16 + (lane & 15);
  Wf[t] = f2bu(gw[l*4096 + k*64 + c]);
}

// b0[i,:] = bf16( sum_f atom_emb[f, x[i,f], :] + vn_emb[:] )
__global__ void k_encode_nodes(const int* __restrict__ x, const float* __restrict__ atom_emb,
                               const float* __restrict__ vn_emb,
                               unsigned short* __restrict__ b0, int n){
  int t = blockIdx.x * 256 + threadIdx.x;
  int i = t >> 6, j = t & 63;
  if (i >= n) return;
  float acc = vn_emb[j];
  #pragma unroll
  for (int f = 0; f < 9; ++f){
    int idx = x[i*9 + f];
    acc += atom_emb[(f*64 + idx)*64 + j];
  }
  b0[t] = f2bu(acc);
}

// ee[e,:] = bf16(bond-embedding sum) in CSR-sorted edge order (reused 4 layers)
__global__ __launch_bounds__(256) void k_edge_emb(const int* __restrict__ attr_sorted,
                                                  const float* __restrict__ bond,
                                                  unsigned short* __restrict__ ee, int E){
  __shared__ float Bs[1536];
  for (int idx = threadIdx.x; idx < 1536; idx += 256) Bs[idx] = bond[idx];
  __syncthreads();
  long total = (long)E * 64;
  for (long t = (long)blockIdx.x*256 + threadIdx.x; t < total; t += (long)gridDim.x*256){
    int e = (int)(t >> 6), j = (int)(t & 63);
    int a = attr_sorted[e];
    float v = Bs[(a & 255)*64 + j]
            + Bs[(8 + ((a >> 8) & 255))*64 + j]
            + Bs[(16 + ((a >> 16) & 255))*64 + j];
    ee[t] = f2bu(v);
  }
}

// Online-softmax aggregation only: t = hin + m  (bf16 out). One wave per node.
__global__ __launch_bounds__(256) void k_agg_t(
    const unsigned short* __restrict__ b0, const int* __restrict__ offs,
    const int* __restrict__ src_sorted, const unsigned short* __restrict__ ee,
    unsigned short* __restrict__ tbuf, int n){
  int tid = threadIdx.x;
  int w = tid >> 6, j = tid & 63;
  int v = blockIdx.x * 4 + w;
  if (v >= n) return;
  int e0 = offs[v], e1 = offs[v+1];
  float own = bu2f(b0[(size_t)v*64 + j]);
  float tv;
  if (e1 > e0){
    float mx = -INFINITY, den = 0.f, num = 0.f;
    for (int e = e0; e < e1; e += 8){
      float m[8];
      #pragma unroll
      for (int u = 0; u < 8; ++u){
        int ei = e + u;
        bool valid = ei < e1;
        int idx = valid ? ei : e0;
        int s = src_sorted[idx];
        float eev = bu2f(ee[(size_t)idx*64 + j]);
        float hv  = bu2f(b0[(size_t)s*64 + j]);
        float mm = fmaxf(hv + eev, 0.f) + MSG_EPS;
        m[u] = valid ? mm : -3.0e38f;
      }
      float mb = m[0];
      #pragma unroll
      for (int u = 1; u < 8; ++u) mb = fmaxf(mb, m[u]);
      float nm = fmaxf(mx, mb);
      float sc = __expf(mx - nm);
      den *= sc; num *= sc;
      #pragma unroll
      for (int u = 0; u < 8; ++u){
        float ex = __expf(m[u] - nm);
        den += ex;
        num += ex * m[u];
      }
      mx = nm;
    }
    tv = own + num / fmaxf(den, 1e-16f);
  } else {
    tv = own;                 // deg-0: m = 0 (matches ref isfinite->0)
  }
  tbuf[(size_t)v*64 + j] = f2bu(tv);
}

// MFMA GEMM + bias + residual + LN epilogue. 64 rows/block, 4 waves.
// mode 0: hres = t@W+b (+hres); h2out = relu(LN(.)); mode 1: finalout = LN(.)
__global__ __launch_bounds__(256) void k_gemm_ln(
    const unsigned short* __restrict__ tbuf, const unsigned short* __restrict__ Wf,
    const float* __restrict__ bias, float* __restrict__ hres,
    float* __restrict__ h2out, void* __restrict__ finalout,
    const float* __restrict__ ng, const float* __restrict__ nb,
    const int* __restrict__ flag, int use_res, int mode, int n){
  __shared__ unsigned short sT[64*72];      // t tile, pitch 72 shorts (bank-spread)
  int tid = threadIdx.x;
  int v0 = blockIdx.x * 64;
  {
    const uint4* tg = (const uint4*)tbuf;   // 8 uint4 per 64-bf16 row
    #pragma unroll
    for (int c = 0; c < 2; ++c){
      int chunk = tid*2 + c;                // 0..511
      int row = chunk >> 3, c8 = chunk & 7;
      uint4 val = make_uint4(0,0,0,0);
      if (v0 + row < n) val = tg[(size_t)(v0 + row)*8 + c8];
      *(uint4*)&sT[row*72 + c8*8] = val;
    }
  }
  __syncthreads();
  int w = tid >> 6, lane = tid & 63;
  int quad = lane >> 4, lm = lane & 15;
  uint4 Bfr[2][4];
  const uint4* Wfv = (const uint4*)Wf;      // frag (kt,nt): uint4 idx (kt*4+nt)*64+lane
  #pragma unroll
  for (int kt = 0; kt < 2; ++kt)
    #pragma unroll
    for (int nt = 0; nt < 4; ++nt)
      Bfr[kt][nt] = Wfv[(size_t)((kt*4 + nt)*64 + lane)];
  f4v acc[4];
  #pragma unroll
  for (int nt = 0; nt < 4; ++nt) acc[nt] = (f4v){0.f,0.f,0.f,0.f};
  #pragma unroll
  for (int kt = 0; kt < 2; ++kt){
    uint4 A = *(const uint4*)&sT[(w*16 + lm)*72 + kt*32 + quad*8];
    #pragma unroll
    for (int nt = 0; nt < 4; ++nt)
      acc[nt] = mfma16(A, Bfr[kt][nt], acc[nt]);
  }
  // epilogue: C layout row=quad*4+reg (within wave's 16), col=nt*16+lm
  float c[4][4];
  float s1[4] = {0,0,0,0}, s2[4] = {0,0,0,0};
  #pragma unroll
  for (int nt = 0; nt < 4; ++nt){
    int col = nt*16 + lm;
    float bv = bias[col];
    #pragma unroll
    for (int reg = 0; reg < 4; ++reg){
      int row = v0 + w*16 + quad*4 + reg;
      float val = acc[nt][reg] + bv;
      if (use_res && row < n) val += hres[(size_t)row*64 + col];
      c[nt][reg] = val;
      s1[reg] += val;
      s2[reg] += val*val;
    }
  }
  #pragma unroll
  for (int reg = 0; reg < 4; ++reg){
    #pragma unroll
    for (int m = 1; m < 16; m <<= 1){
      s1[reg] += __shfl_xor(s1[reg], m, 64);
      s2[reg] += __shfl_xor(s2[reg], m, 64);
    }
  }
  bool isf = (mode == 1) && (*flag != 0);
  #pragma unroll
  for (int reg = 0; reg < 4; ++reg){
    int row = v0 + w*16 + quad*4 + reg;
    if (row >= n) continue;
    float mu = s1[reg] * (1.f/64.f);
    float var = fmaxf(s2[reg] * (1.f/64.f) - mu*mu, 0.f);
    float rstd = rsqrtf(var + LN_EPS);
    #pragma unroll
    for (int nt = 0; nt < 4; ++nt){
      int col = nt*16 + lm;
      float val = c[nt][reg];
      float y = (val - mu) * rstd * ng[col] + nb[col];
      size_t o = (size_t)row*64 + col;
      if (mode == 0){
        hres[o] = val;
        h2out[o] = fmaxf(y, 0.f);
      } else {
        if (isf) ((float*)finalout)[o] = y;
        else     ((bf16*)finalout)[o]  = __float2bfloat16(y);
      }
    }
  }
}

// Fused virtualnode update, 4 waves/block
__global__ __launch_bounds__(256) void k_vn(
    const float* __restrict__ h2, const int* __restrict__ goffs,
    const float* __restrict__ vn_emb, float* __restrict__ vn,
    const float* __restrict__ W1, const float* __restrict__ b1,
    const float* __restrict__ g1, const float* __restrict__ be1,
    const float* __restrict__ W2, const float* __restrict__ b2,
    const float* __restrict__ g2, const float* __restrict__ be2,
    int first){
  __shared__ float Ws[4096];
  __shared__ float part[4][64];
  __shared__ float rowbuf[64];
  int tid = threadIdx.x, w = tid >> 6, j = tid & 63, g = blockIdx.x;
  for (int idx = tid; idx < 4096; idx += 256) Ws[idx] = W1[idx];
  int r0 = goffs[g], r1 = goffs[g+1];
  float sum = 0.f;
  for (int i = r0 + w; i < r1; i += 4) sum += h2[(size_t)i*64 + j];
  part[w][j] = sum;
  __syncthreads();
  float y = 0.f;
  if (tid < 64){
    float s = part[0][j] + part[1][j] + part[2][j] + part[3][j]
            + (first ? vn_emb[j] : vn[(size_t)g*64 + j]);
    rowbuf[j] = s;
  }
  __syncthreads();
  if (tid < 64){
    float acc = b1[j];
    #pragma unroll
    for (int k = 0; k < 64; ++k) acc = fmaf(rowbuf[k], Ws[k*64 + j], acc);
    float mu = wave_sum64(acc) * (1.f/64.f);
    float d = acc - mu;
    float var = wave_sum64(d*d) * (1.f/64.f);
    y = fmaxf(d * rsqrtf(var + LN_EPS) * g1[j] + be1[j], 0.f);
  }
  __syncthreads();
  for (int idx = tid; idx < 4096; idx += 256) Ws[idx] = W2[idx];
  if (tid < 64) rowbuf[j] = y;
  __syncthreads();
  if (tid < 64){
    float acc = b2[j];
    #pragma unroll
    for (int k = 0; k < 64; ++k) acc = fmaf(rowbuf[k], Ws[k*64 + j], acc);
    float mu = wave_sum64(acc) * (1.f/64.f);
    float d = acc - mu;
    float var = wave_sum64(d*d) * (1.f/64.f);
    vn[(size_t)g*64 + j] = fmaxf(d * rsqrtf(var + LN_EPS) * g2[j] + be2[j], 0.f);
  }
}

// b0 = bf16(h2 + vn[batch])
__global__ void k_addvn(const float* __restrict__ h2, const float* __restrict__ vn,
                        const int* __restrict__ batch, unsigned short* __restrict__ b0, int n){
  int t = blockIdx.x * 256 + threadIdx.x;
  int i = t >> 6, j = t & 63;
  if (i >= n) return;
  b0[t] = f2bu(h2[t] + vn[(size_t)batch[i]*64 + j]);
}

extern "C" void kernel_launch(void* const* d_in, const int* in_sizes, int n_in,
                              void* d_out, int out_size, void* d_ws, size_t ws_size,
                              hipStream_t stream){
  const int* x          = (const int*)d_in[0];
  const int* edge_index = (const int*)d_in[1];
  const int* edge_attr  = (const int*)d_in[2];
  const int* batch      = (const int*)d_in[3];

  const int N = in_sizes[3];
  const int E = in_sizes[2] / 3;
  const int L = 4;

  const int P_ATOM = 0, P_BOND = 36864, P_GW = 38400, P_GB = 54784,
            P_NG = 55040, P_NB = 55296, P_VNE = 55552, P_W1 = 55616,
            P_B1 = 67904, P_G1 = 68096, P_BE1 = 68288, P_W2 = 68480,
            P_B2 = 80768, P_G2 = 80960, P_BE2 = 81152, P_END = 81344;

  char* ws = (char*)d_ws;
  size_t off = 0;
  auto alloc = [&](size_t bytes)->char*{
    char* p = ws + off; off += (bytes + 255) & ~(size_t)255; return p;
  };
  int*    flag   = (int*)alloc(256);
  float*  par    = (float*)alloc((size_t)P_END * 4);
  unsigned short* Wf = (unsigned short*)alloc(16384 * 2);
  unsigned short* b0 = (unsigned short*)alloc((size_t)N*64*2);
  unsigned short* tb = (unsigned short*)alloc((size_t)N*64*2);
  float*  h      = (float*)alloc((size_t)N*64*4);
  float*  h2     = (float*)alloc((size_t)N*64*4);
  unsigned short* ee = (unsigned short*)alloc((size_t)E*64*2);
  int*    counts = (int*)alloc((size_t)N*4);
  int*    offs   = (int*)alloc((size_t)(N+1)*4);
  int*    cursor = (int*)alloc((size_t)N*4);
  int*    btot   = (int*)alloc(1024);
  int*    bexc   = (int*)alloc(1024);
  int*    src_s  = (int*)alloc((size_t)E*4);
  int*    attr_s = (int*)alloc((size_t)E*4);
  int*    goffs  = (int*)alloc((size_t)(GNUM+1)*4);
  float*  vn     = (float*)alloc((size_t)GNUM*64*4);
  (void)ws_size; (void)n_in; (void)out_size;

  Params15 P;
  const int poffs[15] = {P_ATOM,P_BOND,P_GW,P_GB,P_NG,P_NB,P_VNE,P_W1,P_B1,P_G1,P_BE1,P_W2,P_B2,P_G2,P_BE2};
  for (int a = 0; a < 15; ++a){ P.src[a] = d_in[4+a]; P.n[a] = in_sizes[4+a]; P.off[a] = poffs[a]; }

  int nodeGrid = (N*64 + 255) / 256;
  int nScanB   = (N + 255) / 256;
  int eGrid    = (E + 255) / 256;
  const int* srcp = edge_index;
  const int* dstp = edge_index + E;

  k_detect<<<1, 64, 0, stream>>>((const unsigned short*)d_in[4], flag);
  k_convert<<<64, 256, 0, stream>>>(P, flag, par);

  hipMemsetAsync(counts, 0, (size_t)N*4, stream);
  k_count<<<eGrid, 256, 0, stream>>>(dstp, counts, E);
  k_scan1<<<nScanB, 256, 0, stream>>>(counts, offs, btot, N);
  k_scan2<<<1, 256, 0, stream>>>(btot, bexc, nScanB);
  k_scan3<<<nScanB, 256, 0, stream>>>(offs, bexc, N);
  hipMemcpyAsync(cursor, offs, (size_t)N*4, hipMemcpyDeviceToDevice, stream);
  k_scatter<<<eGrid, 256, 0, stream>>>(srcp, dstp, edge_attr, cursor, src_s, attr_s, E);
  k_goffs<<<2, 256, 0, stream>>>(batch, goffs, N);
  k_prep_w<<<64, 256, 0, stream>>>(par + P_GW, Wf);
  k_encode_nodes<<<nodeGrid, 256, 0, stream>>>(x, par + P_ATOM, par + P_VNE, b0, N);
  k_edge_emb<<<1024, 256, 0, stream>>>(attr_s, par + P_BOND, ee, E);

  int gemmGrid = (N + 63) / 64;
  for (int l = 0; l < L; ++l){
    if (l > 0){
      k_vn<<<GNUM, 256, 0, stream>>>(h2, goffs, par + P_VNE, vn,
                                     par + P_W1 + (l-1)*4096, par + P_B1 + (l-1)*64,
                                     par + P_G1 + (l-1)*64, par + P_BE1 + (l-1)*64,
                                     par + P_W2 + (l-1)*4096, par + P_B2 + (l-1)*64,
                                     par + P_G2 + (l-1)*64, par + P_BE2 + (l-1)*64,
                                     l == 1 ? 1 : 0);
      k_addvn<<<nodeGrid, 256, 0, stream>>>(h2, vn, batch, b0, N);
    }
    k_agg_t<<<(N + 3)/4, 256, 0, stream>>>(b0, offs, src_s, ee, tb, N);
    int mode = (l == L-1) ? 1 : 0;
    k_gemm_ln<<<gemmGrid, 256, 0, stream>>>(tb, Wf + (size_t)l*4096,
                                            par + P_GB + l*64, h, h2, d_out,
                                            par + P_NG + l*64, par + P_NB + l*64,
                                            flag, l > 0 ? 1 : 0, mode, N);
  }
}